// Round 2
// baseline (432.277 us; speedup 1.0000x reference)
//
#include <hip/hip_runtime.h>

typedef __attribute__((ext_vector_type(8))) short s8v;
typedef __attribute__((ext_vector_type(4))) float f4;

#define SEQ 1024
#define BATCH 2048

// Split (a,b) into a bf16 hi-plane word and bf16 lo-plane (residual) word.
// Word layout: low16 = a's bf16, high16 = b's bf16. Pure bit ops (truncation
// split) — no dependence on cvt_pk operand order or rounding mode.
__device__ __forceinline__ void splitpk(float a, float b, unsigned &hw, unsigned &lw) {
  unsigned au = __float_as_uint(a), bu = __float_as_uint(b);
  hw = (au >> 16) | (bu & 0xffff0000u);
  float la = a - __uint_as_float(au & 0xffff0000u);
  float lb = b - __uint_as_float(bu & 0xffff0000u);
  lw = (__float_as_uint(la) >> 16) | (__float_as_uint(lb) & 0xffff0000u);
}

__device__ __forceinline__ f4 MF(const unsigned (&a)[4], const unsigned (&b)[4], f4 c) {
  union U { unsigned u[4]; s8v v; } A, B;
  A.u[0] = a[0]; A.u[1] = a[1]; A.u[2] = a[2]; A.u[3] = a[3];
  B.u[0] = b[0]; B.u[1] = b[1]; B.u[2] = b[2]; B.u[3] = b[3];
  return __builtin_amdgcn_mfma_f32_16x16x32_bf16(A.v, B.v, c, 0, 0, 0);
}

// k-map convention (applied identically to A and B operands, so any mismatch
// with the true HW map cancels): element i of lane-group g sits at
//   k = 4*g + i          for i in [0,4)
//   k = 16 + 4*g + (i-4) for i in [4,8)
// This makes the C-layout (row = 4g + reg) feed the next B-fragment with NO
// cross-lane movement: word w of the B-frag = pack(c[2w'], c[2w'+1]).

// Convert C-layout f32 results (va = rows 4g+r, vb = rows 16+4g+r, col=lane&15)
// into a B-fragment (col = lane&15) under the k-map above, as hi/lo planes.
__device__ __forceinline__ void conv(f4 va, f4 vb, unsigned (&hi)[4], unsigned (&lo)[4]) {
  splitpk(va[0], va[1], hi[0], lo[0]);
  splitpk(va[2], va[3], hi[1], lo[1]);
  splitpk(vb[0], vb[1], hi[2], lo[2]);
  splitpk(vb[2], vb[3], hi[3], lo[3]);
}

// Load an A fragment (row fixed per lane) under the same k-map, hi/lo split.
__device__ __forceinline__ void loadA(const float* W, int row, int g,
                                      unsigned (&hi)[4], unsigned (&lo)[4]) {
  const float* p = W + row * 32;
  f4 u = *(const f4*)(p + 4 * g);
  f4 v = *(const f4*)(p + 16 + 4 * g);
  splitpk(u[0], u[1], hi[0], lo[0]);
  splitpk(u[2], u[3], hi[1], lo[1]);
  splitpk(v[0], v[1], hi[2], lo[2]);
  splitpk(v[2], v[3], hi[3], lo[3]);
}

__global__ __launch_bounds__(64) void rnn_fused(
    const float* __restrict__ x,    const float* __restrict__ h0,
    const float* __restrict__ Wih0, const float* __restrict__ Whh0,
    const float* __restrict__ bih0, const float* __restrict__ bhh0,
    const float* __restrict__ Wih1, const float* __restrict__ Whh1,
    const float* __restrict__ bih1, const float* __restrict__ bhh1,
    const float* __restrict__ Wout, const float* __restrict__ boutp,
    float* __restrict__ out)
{
  const int lane = threadIdx.x;
  const int c = lane & 15;      // batch column within tile (also A-frag row)
  const int g = lane >> 4;      // lane group 0..3
  const int b = blockIdx.x * 16 + c;

  // Weight A-fragments (hi/lo split), rows 0-15 and 16-31 per matrix.
  unsigned W00h[4], W00l[4], W01h[4], W01l[4];
  unsigned Wi10h[4], Wi10l[4], Wi11h[4], Wi11l[4];
  unsigned Wh10h[4], Wh10l[4], Wh11h[4], Wh11l[4];
  loadA(Whh0, c,      g, W00h,  W00l);
  loadA(Whh0, 16 + c, g, W01h,  W01l);
  loadA(Wih1, c,      g, Wi10h, Wi10l);
  loadA(Wih1, 16 + c, g, Wi11h, Wi11l);
  loadA(Whh1, c,      g, Wh10h, Wh10l);
  loadA(Whh1, 16 + c, g, Wh11h, Wh11l);

  // Output-projection A-fragment: broadcast Wout to every row (row-independent),
  // so D[row][col] = out[col] for every row — no cross-lane reduction needed.
  unsigned WOh[4], WOl[4];
  {
    f4 u = *(const f4*)(Wout + 4 * g);
    f4 v = *(const f4*)(Wout + 16 + 4 * g);
    splitpk(u[0], u[1], WOh[0], WOl[0]);
    splitpk(u[2], u[3], WOh[1], WOl[1]);
    splitpk(v[0], v[1], WOh[2], WOl[2]);
    splitpk(v[2], v[3], WOh[3], WOl[3]);
  }

  // Hidden-state B-fragments (col = c), hi/lo split, same k-map.
  unsigned B1h[4], B1l[4], B2h[4], B2l[4];
  {
    const float* p1 = h0 + b * 32;
    f4 u = *(const f4*)(p1 + 4 * g);
    f4 v = *(const f4*)(p1 + 16 + 4 * g);
    splitpk(u[0], u[1], B1h[0], B1l[0]);
    splitpk(u[2], u[3], B1h[1], B1l[1]);
    splitpk(v[0], v[1], B1h[2], B1l[2]);
    splitpk(v[2], v[3], B1h[3], B1l[3]);
    const float* p2 = p1 + BATCH * 32;
    f4 u2 = *(const f4*)(p2 + 4 * g);
    f4 v2 = *(const f4*)(p2 + 16 + 4 * g);
    splitpk(u2[0], u2[1], B2h[0], B2l[0]);
    splitpk(u2[2], u2[3], B2h[1], B2l[1]);
    splitpk(v2[0], v2[1], B2h[2], B2l[2]);
    splitpk(v2[2], v2[3], B2h[3], B2l[3]);
  }

  // Per-lane row constants (C-layout rows: set0 = 4g+r, set1 = 16+4g+r), fp32.
  f4 wih0A, wih0B, b0A, b0B, b1A, b1B;
#pragma unroll
  for (int r = 0; r < 4; ++r) {
    int j0 = 4 * g + r, j1 = 16 + 4 * g + r;
    wih0A[r] = Wih0[j0];              wih0B[r] = Wih0[j1];
    b0A[r]   = bih0[j0] + bhh0[j0];   b0B[r]   = bih0[j1] + bhh0[j1];
    b1A[r]   = bih1[j0] + bhh1[j0];   b1B[r]   = bih1[j1] + bhh1[j1];
  }
  const float bO = boutp[0];
  const f4 z = {0.f, 0.f, 0.f, 0.f};

  f4 v10, v11, v20, v21;   // persistent: last step's relu outputs (f32, C layout)

  auto STEP = [&](int T, float XV) {
    // ---- layer 0: h1n = relu(x*Wih0 + b0 + Whh0 @ h1) ----
    f4 c00, c01;
#pragma unroll
    for (int r = 0; r < 4; ++r) {
      c00[r] = fmaf(XV, wih0A[r], b0A[r]);
      c01[r] = fmaf(XV, wih0B[r], b0B[r]);
    }
    c00 = MF(W00h, B1h, c00);  c01 = MF(W01h, B1h, c01);
    c00 = MF(W00h, B1l, c00);  c01 = MF(W01h, B1l, c01);
    c00 = MF(W00l, B1h, c00);  c01 = MF(W01l, B1h, c01);
#pragma unroll
    for (int r = 0; r < 4; ++r) {
      v10[r] = fmaxf(c00[r], 0.f);
      v11[r] = fmaxf(c01[r], 0.f);
    }
    conv(v10, v11, B1h, B1l);   // h1n -> B fragment (no cross-lane)

    // ---- layer 1: h2n = relu(Wih1 @ h1n + b1 + Whh1 @ h2) ----
    f4 cA0 = MF(Wi10h, B1h, b1A);
    f4 cA1 = MF(Wi11h, B1h, b1B);
    cA0 = MF(Wi10h, B1l, cA0);  cA1 = MF(Wi11h, B1l, cA1);
    cA0 = MF(Wi10l, B1h, cA0);  cA1 = MF(Wi11l, B1h, cA1);
    f4 cB0 = MF(Wh10h, B2h, z);
    f4 cB1 = MF(Wh11h, B2h, z);
    cB0 = MF(Wh10h, B2l, cB0);  cB1 = MF(Wh11h, B2l, cB1);
    cB0 = MF(Wh10l, B2h, cB0);  cB1 = MF(Wh11l, B2h, cB1);
#pragma unroll
    for (int r = 0; r < 4; ++r) {
      v20[r] = fmaxf(cA0[r] + cB0[r], 0.f);
      v21[r] = fmaxf(cA1[r] + cB1[r], 0.f);
    }
    conv(v20, v21, B2h, B2l);   // h2n -> B fragment (no cross-lane)

    // ---- output: out[t,b] = dot(Wout, h2n) + b_out, via broadcast-A MFMA ----
    f4 cO = MF(WOh, B2h, z);
    cO = MF(WOh, B2l, cO);
    cO = MF(WOl, B2h, cO);
    if (g == 0) out[T * BATCH + b] = cO[0] + bO;
  };

  // x prefetch depth 4 (index clamped so the tail loads stay in-bounds)
  float xa = x[0 * BATCH + b];
  float xb = x[1 * BATCH + b];
  float xc = x[2 * BATCH + b];
  float xd = x[3 * BATCH + b];

#pragma unroll 1
  for (int t = 0; t < SEQ; t += 4) {
    STEP(t + 0, xa); { int ti = (t + 4 < SEQ) ? t + 4 : SEQ - 1; xa = x[ti * BATCH + b]; }
    STEP(t + 1, xb); { int ti = (t + 5 < SEQ) ? t + 5 : SEQ - 1; xb = x[ti * BATCH + b]; }
    STEP(t + 2, xc); { int ti = (t + 6 < SEQ) ? t + 6 : SEQ - 1; xc = x[ti * BATCH + b]; }
    STEP(t + 3, xd); { int ti = (t + 7 < SEQ) ? t + 7 : SEQ - 1; xd = x[ti * BATCH + b]; }
  }

  // final hidden state (f32 values from the last step, C layout rows)
  float* hs = out + SEQ * BATCH;
  *(f4*)(hs + b * 32 + 4 * g)                    = v10;
  *(f4*)(hs + b * 32 + 16 + 4 * g)               = v11;
  *(f4*)(hs + BATCH * 32 + b * 32 + 4 * g)       = v20;
  *(f4*)(hs + BATCH * 32 + b * 32 + 16 + 4 * g)  = v21;
}

extern "C" void kernel_launch(void* const* d_in, const int* in_sizes, int n_in,
                              void* d_out, int out_size, void* d_ws, size_t ws_size,
                              hipStream_t stream) {
  rnn_fused<<<dim3(128), dim3(64), 0, stream>>>(
      (const float*)d_in[0],  (const float*)d_in[1],  (const float*)d_in[2],
      (const float*)d_in[3],  (const float*)d_in[4],  (const float*)d_in[5],
      (const float*)d_in[6],  (const float*)d_in[7],  (const float*)d_in[8],
      (const float*)d_in[9],  (const float*)d_in[10], (const float*)d_in[11],
      (float*)d_out);
}